// Round 1
// baseline (585.587 us; speedup 1.0000x reference)
//
#include <hip/hip_runtime.h>
#include <math.h>

#define F 32
#define K 16
#define EPSN 1e-8f

template<int DEG>
__global__ __launch_bounds__(256)
void score_kernel(const float* __restrict__ x,
                  const int*   __restrict__ sel,
                  const int*   __restrict__ nei,
                  const float* __restrict__ Wf,
                  const float* __restrict__ Wn,
                  float* __restrict__ out,
                  int nd)
{
    constexpr int NW = K * (1 + DEG);        // W rows: 16 focal + 16*DEG neighbor
    __shared__ float sW[NW * F];

    const int tid = threadIdx.x;

    // --- normalize W rows into LDS (rows 0..15 = Wf, 16.. = Wn flat (k*DEG+j)) ---
    if (tid < NW) {
        const float* src = (tid < K) ? (Wf + tid * F) : (Wn + (tid - K) * F);
        float ss = 0.f;
        #pragma unroll
        for (int f = 0; f < F; ++f) { float v = src[f]; ss += v * v; }
        const float sc = 1.f / (sqrtf(ss) + EPSN);
        #pragma unroll
        for (int f = 0; f < F; ++f) sW[tid * F + f] = src[f] * sc;
    }
    __syncthreads();

    const int i = blockIdx.x * 256 + tid;
    if (i >= nd) return;

    const int node = sel[i];
    float acc[K];

    // --- focal row ---
    {
        const float4* xr = (const float4*)(x + (size_t)node * F);
        float4 r[F / 4];
        #pragma unroll
        for (int q = 0; q < F / 4; ++q) r[q] = xr[q];
        float ss = 0.f;
        #pragma unroll
        for (int q = 0; q < F / 4; ++q)
            ss += r[q].x * r[q].x + r[q].y * r[q].y + r[q].z * r[q].z + r[q].w * r[q].w;
        const float sc = 1.f / (sqrtf(ss) + EPSN);
        #pragma unroll
        for (int k = 0; k < K; ++k) {
            float s = 0.f;
            #pragma unroll
            for (int q = 0; q < F / 4; ++q) {
                const float4 w = *(const float4*)&sW[k * F + q * 4];  // wave-uniform broadcast
                s += w.x * r[q].x + w.y * r[q].y + w.z * r[q].z + w.w * r[q].w;
            }
            acc[k] = s * sc;
        }
    }

    // --- neighbor rows: Wn row for (k, j) lives at LDS row (K + k*DEG + j) ---
    #pragma unroll
    for (int j = 0; j < DEG; ++j) {
        const int nn = nei[i * DEG + j];
        const float4* xr = (const float4*)(x + (size_t)nn * F);
        float4 r[F / 4];
        #pragma unroll
        for (int q = 0; q < F / 4; ++q) r[q] = xr[q];
        float ss = 0.f;
        #pragma unroll
        for (int q = 0; q < F / 4; ++q)
            ss += r[q].x * r[q].x + r[q].y * r[q].y + r[q].z * r[q].z + r[q].w * r[q].w;
        const float sc = (1.f / (sqrtf(ss) + EPSN)) * (1.f / (float)DEG);
        #pragma unroll
        for (int k = 0; k < K; ++k) {
            float s = 0.f;
            #pragma unroll
            for (int q = 0; q < F / 4; ++q) {
                const float4 w = *(const float4*)&sW[(K + k * DEG + j) * F + q * 4];
                s += w.x * r[q].x + w.y * r[q].y + w.z * r[q].z + w.w * r[q].w;
            }
            acc[k] += s * sc;
        }
    }

    // --- write full 64-float output row: zeros except this degree's 16-block ---
    float4* o = (float4*)(out + (size_t)node * (4 * K));
    const float4 z = make_float4(0.f, 0.f, 0.f, 0.f);
    #pragma unroll
    for (int b = 0; b < 4; ++b) {
        if (b == DEG - 1) {
            o[b * 4 + 0] = make_float4(acc[0],  acc[1],  acc[2],  acc[3]);
            o[b * 4 + 1] = make_float4(acc[4],  acc[5],  acc[6],  acc[7]);
            o[b * 4 + 2] = make_float4(acc[8],  acc[9],  acc[10], acc[11]);
            o[b * 4 + 3] = make_float4(acc[12], acc[13], acc[14], acc[15]);
        } else {
            o[b * 4 + 0] = z; o[b * 4 + 1] = z; o[b * 4 + 2] = z; o[b * 4 + 3] = z;
        }
    }
}

extern "C" void kernel_launch(void* const* d_in, const int* in_sizes, int n_in,
                              void* d_out, int out_size, void* d_ws, size_t ws_size,
                              hipStream_t stream)
{
    const float* x = (const float*)d_in[0];
    float* out = (float*)d_out;

    // dict order: x, then per degree d: selected, nei, W_focal, W_nei
    const int*   sel1 = (const int*)  d_in[1];
    const int*   nei1 = (const int*)  d_in[2];
    const float* Wf1  = (const float*)d_in[3];
    const float* Wn1  = (const float*)d_in[4];
    const int*   sel2 = (const int*)  d_in[5];
    const int*   nei2 = (const int*)  d_in[6];
    const float* Wf2  = (const float*)d_in[7];
    const float* Wn2  = (const float*)d_in[8];
    const int*   sel3 = (const int*)  d_in[9];
    const int*   nei3 = (const int*)  d_in[10];
    const float* Wf3  = (const float*)d_in[11];
    const float* Wn3  = (const float*)d_in[12];
    const int*   sel4 = (const int*)  d_in[13];
    const int*   nei4 = (const int*)  d_in[14];
    const float* Wf4  = (const float*)d_in[15];
    const float* Wn4  = (const float*)d_in[16];

    const int nd1 = in_sizes[1];
    const int nd2 = in_sizes[5];
    const int nd3 = in_sizes[9];
    const int nd4 = in_sizes[13];

    score_kernel<1><<<(nd1 + 255) / 256, 256, 0, stream>>>(x, sel1, nei1, Wf1, Wn1, out, nd1);
    score_kernel<2><<<(nd2 + 255) / 256, 256, 0, stream>>>(x, sel2, nei2, Wf2, Wn2, out, nd2);
    score_kernel<3><<<(nd3 + 255) / 256, 256, 0, stream>>>(x, sel3, nei3, Wf3, Wn3, out, nd3);
    score_kernel<4><<<(nd4 + 255) / 256, 256, 0, stream>>>(x, sel4, nei4, Wf4, Wn4, out, nd4);
}

// Round 2
// 580.307 us; speedup vs baseline: 1.0091x; 1.0091x over previous
//
#include <hip/hip_runtime.h>
#include <math.h>

#define F 32
#define K 16
#define EPSN 1e-8f

// Per-degree worker: block handles 256 consecutive focal nodes of one degree.
// sW: per-block LDS holding the normalized W rows for this degree
// (rows 0..15 = W_focal, rows 16.. = W_nei flat (k*DEG+j)).
template<int DEG>
__device__ __forceinline__ void process_deg(const float* __restrict__ x,
                                            const int*   __restrict__ sel,
                                            const int*   __restrict__ nei,
                                            const float* __restrict__ Wf,
                                            const float* __restrict__ Wn,
                                            float* __restrict__ out,
                                            int nd, int i0, float* sW)
{
    constexpr int NW = K * (1 + DEG);
    const int tid = threadIdx.x;

    // normalize W rows into LDS (one thread per row; NW <= 80)
    if (tid < NW) {
        const float* src = (tid < K) ? (Wf + tid * F) : (Wn + (tid - K) * F);
        float ss = 0.f;
        #pragma unroll
        for (int f = 0; f < F; ++f) { float v = src[f]; ss += v * v; }
        const float sc = 1.f / (sqrtf(ss) + EPSN);
        #pragma unroll
        for (int f = 0; f < F; ++f) sW[tid * F + f] = src[f] * sc;
    }
    __syncthreads();

    const int i = i0 + tid;
    if (i >= nd) return;

    const int node = sel[i];

    // hoist neighbor index loads so they issue before/with the focal gather
    int nn[DEG];
    #pragma unroll
    for (int j = 0; j < DEG; ++j) nn[j] = nei[i * DEG + j];

    float acc[K];

    // --- focal row ---
    {
        const float4* xr = (const float4*)(x + (size_t)node * F);
        float4 r[F / 4];
        #pragma unroll
        for (int q = 0; q < F / 4; ++q) r[q] = xr[q];
        float ss = 0.f;
        #pragma unroll
        for (int q = 0; q < F / 4; ++q)
            ss += r[q].x * r[q].x + r[q].y * r[q].y + r[q].z * r[q].z + r[q].w * r[q].w;
        const float sc = 1.f / (sqrtf(ss) + EPSN);
        #pragma unroll
        for (int k = 0; k < K; ++k) {
            float s = 0.f;
            #pragma unroll
            for (int q = 0; q < F / 4; ++q) {
                const float4 w = *(const float4*)&sW[k * F + q * 4];  // uniform broadcast
                s += w.x * r[q].x + w.y * r[q].y + w.z * r[q].z + w.w * r[q].w;
            }
            acc[k] = s * sc;
        }
    }

    // --- neighbor rows ---
    #pragma unroll
    for (int j = 0; j < DEG; ++j) {
        const float4* xr = (const float4*)(x + (size_t)nn[j] * F);
        float4 r[F / 4];
        #pragma unroll
        for (int q = 0; q < F / 4; ++q) r[q] = xr[q];
        float ss = 0.f;
        #pragma unroll
        for (int q = 0; q < F / 4; ++q)
            ss += r[q].x * r[q].x + r[q].y * r[q].y + r[q].z * r[q].z + r[q].w * r[q].w;
        const float sc = (1.f / (sqrtf(ss) + EPSN)) * (1.f / (float)DEG);
        #pragma unroll
        for (int k = 0; k < K; ++k) {
            float s = 0.f;
            #pragma unroll
            for (int q = 0; q < F / 4; ++q) {
                const float4 w = *(const float4*)&sW[(K + k * DEG + j) * F + q * 4];
                s += w.x * r[q].x + w.y * r[q].y + w.z * r[q].z + w.w * r[q].w;
            }
            acc[k] += s * sc;
        }
    }

    // --- write full 64-float output row (zeros outside this degree's block) ---
    float4* o = (float4*)(out + (size_t)node * (4 * K));
    const float4 z = make_float4(0.f, 0.f, 0.f, 0.f);
    #pragma unroll
    for (int b = 0; b < 4; ++b) {
        if (b == DEG - 1) {
            o[b * 4 + 0] = make_float4(acc[0],  acc[1],  acc[2],  acc[3]);
            o[b * 4 + 1] = make_float4(acc[4],  acc[5],  acc[6],  acc[7]);
            o[b * 4 + 2] = make_float4(acc[8],  acc[9],  acc[10], acc[11]);
            o[b * 4 + 3] = make_float4(acc[12], acc[13], acc[14], acc[15]);
        } else {
            o[b * 4 + 0] = z; o[b * 4 + 1] = z; o[b * 4 + 2] = z; o[b * 4 + 3] = z;
        }
    }
}

struct Args {
    const float* x;
    const int*   sel[4];
    const int*   nei[4];
    const float* Wf[4];
    const float* Wn[4];
    int nd[4];
    int bcum[4];   // cumulative block counts: after deg1, deg1+2, ...
};

__global__ __launch_bounds__(256)
void fused_kernel(Args a, float* __restrict__ out)
{
    __shared__ float sW[K * 5 * F];   // max NW (deg4: 80 rows) * 32 = 10 KB
    const int bid = blockIdx.x;

    if (bid < a.bcum[0]) {
        process_deg<1>(a.x, a.sel[0], a.nei[0], a.Wf[0], a.Wn[0], out,
                       a.nd[0], bid * 256, sW);
    } else if (bid < a.bcum[1]) {
        process_deg<2>(a.x, a.sel[1], a.nei[1], a.Wf[1], a.Wn[1], out,
                       a.nd[1], (bid - a.bcum[0]) * 256, sW);
    } else if (bid < a.bcum[2]) {
        process_deg<3>(a.x, a.sel[2], a.nei[2], a.Wf[2], a.Wn[2], out,
                       a.nd[2], (bid - a.bcum[1]) * 256, sW);
    } else {
        process_deg<4>(a.x, a.sel[3], a.nei[3], a.Wf[3], a.Wn[3], out,
                       a.nd[3], (bid - a.bcum[2]) * 256, sW);
    }
}

extern "C" void kernel_launch(void* const* d_in, const int* in_sizes, int n_in,
                              void* d_out, int out_size, void* d_ws, size_t ws_size,
                              hipStream_t stream)
{
    Args a;
    a.x = (const float*)d_in[0];
    for (int d = 0; d < 4; ++d) {
        a.sel[d] = (const int*)  d_in[1 + 4 * d];
        a.nei[d] = (const int*)  d_in[2 + 4 * d];
        a.Wf[d]  = (const float*)d_in[3 + 4 * d];
        a.Wn[d]  = (const float*)d_in[4 + 4 * d];
        a.nd[d]  = in_sizes[1 + 4 * d];
    }
    int cum = 0;
    for (int d = 0; d < 4; ++d) {
        cum += (a.nd[d] + 255) / 256;
        a.bcum[d] = cum;
    }
    float* out = (float*)d_out;
    fused_kernel<<<cum, 256, 0, stream>>>(a, out);
}